// Round 7
// baseline (187.745 us; speedup 1.0000x reference)
//
#include <hip/hip_runtime.h>
#include <math.h>
#include <stdint.h>

#define BROWS 4096
#define VCOLS 50257
#define KTOP  64
#define CAP   2048      // per-row LDS candidate buffer (floats) = 8KB
#define CHECK_AT 1024   // compact when cnt may overflow next 1024-elem half-tile
#define NREG 32         // CAP / 64 lanes

// Order-preserving float->uint key (monotone total order, handles negatives/inf)
__device__ __forceinline__ unsigned f2key(float f) {
    unsigned u = __float_as_uint(f);
    return u ^ ((unsigned)((int)u >> 31) | 0x80000000u);
}
__device__ __forceinline__ float key2f(unsigned k) {
    unsigned u = (k & 0x80000000u) ? (k ^ 0x80000000u) : ~k;
    return __uint_as_float(u);
}

__device__ __forceinline__ int wave_sum_i(int c) {
    #pragma unroll
    for (int d = 1; d < 64; d <<= 1) c += __shfl_xor(c, d);
    return c;
}

// Read CAP floats from LDS as keys into 32 regs/lane; slots >= cnt -> key 0.
// Lane-consecutive 16B chunks -> bank-conflict-free.
__device__ __forceinline__ void load_keys(const float* s_buf, unsigned cnt, int lane, unsigned* key) {
    #pragma unroll
    for (int j = 0; j < NREG / 4; ++j) {
        const float4 v = ((const float4*)s_buf)[j * 64 + lane];
        const int base = (j * 64 + lane) * 4;
        key[4*j+0] = (base + 0 < (int)cnt) ? f2key(v.x) : 0u;
        key[4*j+1] = (base + 1 < (int)cnt) ? f2key(v.y) : 0u;
        key[4*j+2] = (base + 2 < (int)cnt) ? f2key(v.z) : 0u;
        key[4*j+3] = (base + 3 < (int)cnt) ? f2key(v.w) : 0u;
    }
}

// Wave-local compaction: keep elements >= approx 64th-largest-so-far.
// NOINLINE + by-value in/out: keeps key[32] register pressure OUT of the hot
// streaming loop (cold call ~6x per row). Returns (cnt<<32)|lo_key.
__device__ __attribute__((noinline)) unsigned long long
wave_compact_f(float* s_buf, unsigned cnt, unsigned lo_in, int lane) {
    __builtin_amdgcn_wave_barrier();
    unsigned key[NREG];
    load_keys(s_buf, cnt, lane, key);
    unsigned kmx = 0u;
    #pragma unroll
    for (int j = 0; j < NREG; ++j) kmx = max(kmx, key[j]);
    #pragma unroll
    for (int d = 1; d < 64; d <<= 1) kmx = max(kmx, (unsigned)__shfl_xor((int)kmx, d));

    unsigned lo = lo_in;        // invariant: count(key >= lo) >= 64
    unsigned hi = kmx + 1u;
    for (int it = 0; it < 12; ++it) {       // approximate threshold is fine here
        if (hi - lo <= 1u) break;
        const unsigned mid = lo + ((hi - lo) >> 1);
        int c = 0;
        #pragma unroll
        for (int j = 0; j < NREG; ++j) c += (key[j] >= mid) ? 1 : 0;
        c = wave_sum_i(c);
        if (c >= KTOP) lo = mid; else hi = mid;
    }
    int cl = 0; unsigned sm = 0u;
    #pragma unroll
    for (int j = 0; j < NREG; ++j) { const bool s = key[j] >= lo; sm |= (unsigned)s << j; cl += s ? 1 : 0; }
    int incl = cl;
    #pragma unroll
    for (int d = 1; d < 64; d <<= 1) { const int t = __shfl_up(incl, d); if (lane >= d) incl += t; }
    int pos = incl - cl;
    __builtin_amdgcn_wave_barrier();
    #pragma unroll
    for (int j = 0; j < NREG; ++j) if ((sm >> j) & 1u) s_buf[pos++] = key2f(key[j]);
    const unsigned ncnt = (unsigned)__shfl(incl, 63);
    __builtin_amdgcn_wave_barrier();
    return ((unsigned long long)ncnt << 32) | (unsigned long long)lo;
}

// Exact top-64 + label-smoothed CE over {truth, top64}. Tie-correct via
// boundary multiplicity. Runs once per row, after streaming.
__device__ __forceinline__ float wave_final(const float* s_buf, unsigned cnt, float thr, float tv, int lane) {
    __builtin_amdgcn_wave_barrier();
    unsigned key[NREG];
    load_keys(s_buf, cnt, lane, key);
    unsigned kmx = 0u;
    #pragma unroll
    for (int j = 0; j < NREG; ++j) kmx = max(kmx, key[j]);
    #pragma unroll
    for (int d = 1; d < 64; d <<= 1) kmx = max(kmx, (unsigned)__shfl_xor((int)kmx, d));

    unsigned lo = f2key(thr);
    unsigned hi = kmx + 1u;
    while (hi - lo > 1u) {
        const unsigned mid = lo + ((hi - lo) >> 1);
        int c = 0;
        #pragma unroll
        for (int j = 0; j < NREG; ++j) c += (key[j] >= mid) ? 1 : 0;
        c = wave_sum_i(c);
        if (c >= KTOP) lo = mid; else hi = mid;
    }
    const float vmax = key2f(kmx);
    const float m = fmaxf(vmax, tv);
    float se = 0.f, sv = 0.f; int cg = 0;
    #pragma unroll
    for (int j = 0; j < NREG; ++j) {
        if (key[j] > lo) { const float v = key2f(key[j]); se += __expf(v - m); sv += v; ++cg; }
    }
    #pragma unroll
    for (int d = 1; d < 64; d <<= 1) {
        se += __shfl_xor(se, d); sv += __shfl_xor(sv, d); cg += __shfl_xor(cg, d);
    }
    const float v64 = key2f(lo);            // exact 64th largest
    const int nb = KTOP - cg;               // boundary multiplicity (>=1)
    se += (float)nb * __expf(v64 - m);
    sv += (float)nb * v64;
    se += __expf(tv - m);
    const float lse = m + __logf(se);
    return lse - 0.9f * tv - 0.1f * ((sv + tv) * (1.0f / 65.0f));
}

// Ballot-aggregated wave insert; cnt is a wave-uniform register (no atomics).
__device__ __forceinline__ void ins1(float v, int gi, int tgt, float thr,
                                     float* s_buf, unsigned& cnt, unsigned long long lt) {
    const bool p = (v > thr) && (gi != tgt);
    const unsigned long long mk = __ballot(p ? 1 : 0);
    if (mk) {
        if (p) {
            const unsigned pos = cnt + (unsigned)__popcll(mk & lt);
            if (pos < CAP) s_buf[pos] = v;
        }
        cnt += (unsigned)__popcll(mk);
    }
}
__device__ __forceinline__ void ins4(const float4 q, int gb, int tgt, float thr,
                                     float* s_buf, unsigned& cnt, unsigned long long lt) {
    ins1(q.x, gb + 0, tgt, thr, s_buf, cnt, lt);
    ins1(q.y, gb + 1, tgt, thr, s_buf, cnt, lt);
    ins1(q.z, gb + 2, tgt, thr, s_buf, cnt, lt);
    ins1(q.w, gb + 3, tgt, thr, s_buf, cnt, lt);
}

// One wave (64-thread block) per row. No __syncthreads, no atomics.
// 8KB contiguous burst per tile (8 x float4 per lane, issued as one cluster),
// processed as two 1024-elem halves so CAP/CHECK_AT invariants hold.
__global__ __launch_bounds__(64) void topk_ce_kernel(
        const float* __restrict__ input, const int* __restrict__ target,
        float* __restrict__ per_ex, float* __restrict__ out_atomic) {
    __shared__ float s_buf[CAP];
    const int row  = blockIdx.x;
    const int lane = threadIdx.x;
    const float* __restrict__ rowp = input + (size_t)row * (size_t)VCOLS;
    const int tgt = target[row];
    const float tv = rowp[tgt];               // independent load, issued early
    const unsigned long long lt = (1ull << lane) - 1ull;

    unsigned cnt = 0u;
    float thr = -INFINITY;

    // Rows are only 4B-aligned (V % 4 == 1): scalar prologue to 16B boundary.
    const int pad = (int)((4u - ((((uintptr_t)rowp) >> 2) & 3u)) & 3u);
    {
        const float v = (lane < pad) ? rowp[lane] : 0.f;
        const bool p = (lane < pad) && (lane != tgt);
        const unsigned long long mk = __ballot(p ? 1 : 0);
        if (p) s_buf[cnt + __popcll(mk & lt)] = v;
        cnt += (unsigned)__popcll(mk);
    }

    const int nvec  = (VCOLS - pad) >> 2;
    const int ntail = (VCOLS - pad) & 3;
    const float4* __restrict__ vp = (const float4*)(rowp + pad);
    const int ntf = nvec >> 9;   // full tiles: 512 quads = 2048 elems

    for (int t = 0; t < ntf; ++t) {
        const int b = (t << 9) + lane;
        // one 8-load burst: 8KB contiguous per wave-turn
        const float4 a0 = vp[b];
        const float4 a1 = vp[b + 64];
        const float4 a2 = vp[b + 128];
        const float4 a3 = vp[b + 192];
        const float4 a4 = vp[b + 256];
        const float4 a5 = vp[b + 320];
        const float4 a6 = vp[b + 384];
        const float4 a7 = vp[b + 448];
        // first half (elements 0..1023 of tile)
        {
            const float m0 = fmaxf(fmaxf(a0.x, a0.y), fmaxf(a0.z, a0.w));
            const float m1 = fmaxf(fmaxf(a1.x, a1.y), fmaxf(a1.z, a1.w));
            const float m2 = fmaxf(fmaxf(a2.x, a2.y), fmaxf(a2.z, a2.w));
            const float m3 = fmaxf(fmaxf(a3.x, a3.y), fmaxf(a3.z, a3.w));
            const float mh = fmaxf(fmaxf(m0, m1), fmaxf(m2, m3));
            if (__ballot((mh > thr) ? 1 : 0)) {
                ins4(a0, pad + 4 * b,         tgt, thr, s_buf, cnt, lt);
                ins4(a1, pad + 4 * (b + 64),  tgt, thr, s_buf, cnt, lt);
                ins4(a2, pad + 4 * (b + 128), tgt, thr, s_buf, cnt, lt);
                ins4(a3, pad + 4 * (b + 192), tgt, thr, s_buf, cnt, lt);
            }
            if (cnt > CHECK_AT) {
                const unsigned long long r = wave_compact_f(s_buf, cnt, f2key(thr), lane);
                cnt = (unsigned)(r >> 32); thr = key2f((unsigned)r);
            }
        }
        // second half (elements 1024..2047 of tile)
        {
            const float m4 = fmaxf(fmaxf(a4.x, a4.y), fmaxf(a4.z, a4.w));
            const float m5 = fmaxf(fmaxf(a5.x, a5.y), fmaxf(a5.z, a5.w));
            const float m6 = fmaxf(fmaxf(a6.x, a6.y), fmaxf(a6.z, a6.w));
            const float m7 = fmaxf(fmaxf(a7.x, a7.y), fmaxf(a7.z, a7.w));
            const float mh = fmaxf(fmaxf(m4, m5), fmaxf(m6, m7));
            if (__ballot((mh > thr) ? 1 : 0)) {
                ins4(a4, pad + 4 * (b + 256), tgt, thr, s_buf, cnt, lt);
                ins4(a5, pad + 4 * (b + 320), tgt, thr, s_buf, cnt, lt);
                ins4(a6, pad + 4 * (b + 384), tgt, thr, s_buf, cnt, lt);
                ins4(a7, pad + 4 * (b + 448), tgt, thr, s_buf, cnt, lt);
            }
            if (cnt > CHECK_AT) {
                const unsigned long long r = wave_compact_f(s_buf, cnt, f2key(thr), lane);
                cnt = (unsigned)(r >> 32); thr = key2f((unsigned)r);
            }
        }
    }

    // masked remainder quads (< 512), uniform trip count
    for (int k0 = ntf << 9; k0 < nvec; k0 += 64) {
        const int idx = k0 + lane;
        float4 a;
        if (idx < nvec) a = vp[idx];
        else { a.x = a.y = a.z = a.w = -INFINITY; }
        const float mA = fmaxf(fmaxf(a.x, a.y), fmaxf(a.z, a.w));
        if (__ballot((mA > thr) ? 1 : 0)) ins4(a, pad + 4 * idx, tgt, thr, s_buf, cnt, lt);
        if (cnt > CHECK_AT) {
            const unsigned long long r = wave_compact_f(s_buf, cnt, f2key(thr), lane);
            cnt = (unsigned)(r >> 32); thr = key2f((unsigned)r);
        }
    }

    // scalar tail (<= 3 elems)
    {
        const int idx = pad + 4 * nvec + lane;
        const float v = (lane < ntail) ? rowp[idx] : 0.f;
        const bool p = (lane < ntail) && (v > thr) && (idx != tgt);
        const unsigned long long mk = __ballot(p ? 1 : 0);
        if (p) {
            const unsigned pos = cnt + (unsigned)__popcll(mk & lt);
            if (pos < CAP) s_buf[pos] = v;
        }
        cnt += (unsigned)__popcll(mk);
    }

    const float pe = wave_final(s_buf, cnt, thr, tv, lane);
    if (lane == 0) {
        if (per_ex) per_ex[row] = pe;
        else atomicAdd(out_atomic, pe * (1.0f / BROWS));
    }
}

// Deterministic mean of the 4096 per-row losses (float4 loads).
__global__ __launch_bounds__(256) void reduce_mean_kernel(
        const float* __restrict__ per_ex, float* __restrict__ out) {
    __shared__ float s[256];
    const int tid = threadIdx.x;
    const float4* p4 = (const float4*)per_ex;
    float acc = 0.0f;
    #pragma unroll
    for (int i = 0; i < BROWS / 1024; ++i) {   // 4 float4 per thread
        const float4 v = p4[i * 256 + tid];
        acc += (v.x + v.y) + (v.z + v.w);
    }
    s[tid] = acc;
    __syncthreads();
    for (int w = 128; w > 0; w >>= 1) {
        if (tid < w) s[tid] += s[tid + w];
        __syncthreads();
    }
    if (tid == 0) out[0] = s[0] * (1.0f / BROWS);
}

extern "C" void kernel_launch(void* const* d_in, const int* in_sizes, int n_in,
                              void* d_out, int out_size, void* d_ws, size_t ws_size,
                              hipStream_t stream) {
    const float* input  = (const float*)d_in[0];
    const int*   target = (const int*)d_in[1];   // jax int64 -> int32 on device (x64 off)
    float* out = (float*)d_out;

    if (ws_size >= BROWS * sizeof(float)) {
        float* per_ex = (float*)d_ws;
        topk_ce_kernel<<<BROWS, 64, 0, stream>>>(input, target, per_ex, nullptr);
        reduce_mean_kernel<<<1, 256, 0, stream>>>(per_ex, out);
    } else {
        hipMemsetAsync(d_out, 0, sizeof(float), stream);
        topk_ce_kernel<<<BROWS, 64, 0, stream>>>(input, target, nullptr, out);
    }
}